// Round 4
// baseline (110.729 us; speedup 1.0000x reference)
//
#include <hip/hip_runtime.h>

#define NUM_A    400000
#define NUM_G    64
#define TOPK     10
#define CHUNKS   32
#define CHUNK_SZ (NUM_A / CHUNKS)   // 12500
#define GGROUP   8                  // GTs per K1 block (= waves per block)
#define NGROUPS  (NUM_G / GGROUP)   // 8
#define NBLOCKS  (CHUNKS * NGROUPS) // 256
#define CAP      1536               // per-GT candidate cap per chunk
                                    // (worst-case mean 500, SD ~22 -> 47 SD)
#define SENT_I   0x7fffffff

// top_k ordering: larger value first; ties -> lower anchor index first.
// Sentinel (0.0f, SENT_I) sorts after every real candidate.
__device__ __forceinline__ bool better(float m1, int a1, float m2, int a2) {
    return (m1 > m2) || ((m1 == m2) && (a1 < a2));
}

// IoU-metric; arithmetic order identical to verified rounds (absmax=0 vs numpy).
__device__ __forceinline__ float iou_metric(
    float px1, float py1, float px2, float py2, float parea, float score,
    float gx1, float gy1, float gx2, float gy2, float garea)
{
    float ltx = fmaxf(px1, gx1);
    float lty = fmaxf(py1, gy1);
    float rbx = fminf(px2, gx2);
    float rby = fminf(py2, gy2);
    float w = fmaxf(rbx - ltx, 0.0f);
    float h = fmaxf(rby - lty, 0.0f);
    float inter = w * h;
    float iou = inter / (parea + garea - inter);   // denom >= 64 always
    float iou2 = iou * iou;
    float iou6 = iou2 * iou2 * iou2;
    return score * iou6;
}

// Wave-wide (64-lane) butterfly max of (value, anchor) under better().
__device__ __forceinline__ void wave_max_pair(float& bv, int& bi) {
#pragma unroll
    for (int s = 1; s < 64; s <<= 1) {
        float ov = __shfl_xor(bv, s, 64);
        int   oi = __shfl_xor(bi, s, 64);
        if (better(ov, oi, bv, bi)) { bv = ov; bi = oi; }
    }
}

// K1: block = (chunk c, gt-group gg), 8 waves (512 threads), 256 blocks.
// Also zeroes the output buffers (folded memset, verified in R1).
// Phase A: in-box test; ballot-compacted append to per-GT LDS candidate lists.
// Phase B: wave j evaluates GT j's candidates into per-lane sorted top-10,
// then 10 rounds of register-only wave-butterfly selection; partials are
// packed (float-bits, idx) int2 — one dwordx2 store/load per pair.
// NOTE (R2 post-mortem): do NOT fuse the merge in here via device-scope
// semaphores — per-block __threadfence() (L2 wb/inv) cost ~75 us. The kernel
// boundary's runtime-managed flush is far cheaper.
__global__ __launch_bounds__(512) void topk_partial_kernel(
    const float* __restrict__ pd_scores,
    const float* __restrict__ pd_bboxes,
    const float* __restrict__ anc_points,
    const float* __restrict__ gt_bboxes,
    int2*  __restrict__ ppack,
    int*   __restrict__ out_zero)      // [fg(A) | idx(A)] to be zeroed
{
    const int c   = blockIdx.x;
    const int gg  = blockIdx.y;
    const int tid = threadIdx.x;
    const int g0  = gg * GGROUP;

    // ---- folded output memset: 200000 int4 over 131072 threads ----
    {
        const int bid = gg * CHUNKS + c;
        for (int t = bid * 512 + tid; t < (2 * NUM_A) / 4; t += NBLOCKS * 512)
            ((int4*)out_zero)[t] = make_int4(0, 0, 0, 0);
    }

    __shared__ int s_cnt[GGROUP];
    __shared__ int s_cand[GGROUP][CAP];

    if (tid < GGROUP) s_cnt[tid] = 0;

    float gx1[GGROUP], gy1[GGROUP], gx2[GGROUP], gy2[GGROUP];
#pragma unroll
    for (int j = 0; j < GGROUP; ++j) {
        float4 gb = ((const float4*)gt_bboxes)[g0 + j];
        gx1[j] = gb.x; gy1[j] = gb.y; gx2[j] = gb.z; gy2[j] = gb.w;
    }
    __syncthreads();

    const int lane = tid & 63;
    const unsigned long long lmlt = (1ull << lane) - 1ull;   // lanemask_lt

    // ---- Phase A: candidate collection (ballot-compacted) ----
    const int p0 = c * (CHUNK_SZ / 2);          // float4 = 2 anchors
    const int p1 = p0 + CHUNK_SZ / 2;
    for (int p = p0 + tid; p < p1; p += 512) {
        float4 aq = ((const float4*)anc_points)[p];
        const int a2 = 2 * p;
#pragma unroll
        for (int j = 0; j < GGROUP; ++j) {
            bool in0 = (aq.x >= gx1[j]) && (aq.x <= gx2[j]) &&
                       (aq.y >= gy1[j]) && (aq.y <= gy2[j]);
            bool in1 = (aq.z >= gx1[j]) && (aq.z <= gx2[j]) &&
                       (aq.w >= gy1[j]) && (aq.w <= gy2[j]);
            unsigned long long b0 = __ballot(in0);
            unsigned long long b1 = __ballot(in1);
            if (b0 | b1) {                       // wave-uniform
                int c0  = __popcll(b0);
                int tot = c0 + __popcll(b1);
                int base;
                if (lane == 0) base = atomicAdd(&s_cnt[j], tot);
                base = __shfl(base, 0, 64);
                if (in0) {
                    int q = base + __popcll(b0 & lmlt);
                    if (q < CAP) s_cand[j][q] = a2;
                }
                if (in1) {
                    int q = base + c0 + __popcll(b1 & lmlt);
                    if (q < CAP) s_cand[j][q] = a2 + 1;
                }
            }
        }
    }
    __syncthreads();

    // ---- Phase B: per-wave candidate evaluation ----
    const int wj = tid >> 6;       // wave = GT within group

    float4 gb = ((const float4*)gt_bboxes)[g0 + wj];   // wave-uniform
    const float garea = (gb.z - gb.x) * (gb.w - gb.y);
    const int n = min(s_cnt[wj], CAP);

    float tv[TOPK]; int ti[TOPK];
#pragma unroll
    for (int k = 0; k < TOPK; ++k) { tv[k] = 0.0f; ti[k] = SENT_I; }

    for (int i = lane; i < n; i += 64) {
        const int a = s_cand[wj][i];
        float4 pb = ((const float4*)pd_bboxes)[a];
        float sc = pd_scores[a];
        float parea = (pb.z - pb.x) * (pb.w - pb.y);
        float m = iou_metric(pb.x, pb.y, pb.z, pb.w, parea, sc,
                             gb.x, gb.y, gb.z, gb.w, garea);
        // list order is arbitrary -> need full (v,idx) compare
        if (better(m, a, tv[TOPK - 1], ti[TOPK - 1])) {
#pragma unroll
            for (int k = TOPK - 1; k >= 1; --k) {
                bool gp = better(m, a, tv[k - 1], ti[k - 1]);
                bool gc = better(m, a, tv[k],     ti[k]);
                tv[k] = gp ? tv[k - 1] : (gc ? m : tv[k]);
                ti[k] = gp ? ti[k - 1] : (gc ? a : ti[k]);
            }
            if (better(m, a, tv[0], ti[0])) { tv[0] = m; ti[0] = a; }
        }
    }

    // ---- 10-round wave selection: 64 sorted lists -> chunk top-10 ----
    float outv = 0.0f; int outi = SENT_I;
#pragma unroll
    for (int k = 0; k < TOPK; ++k) {
        float bv = tv[0]; int bi = ti[0];
        wave_max_pair(bv, bi);
        bool win = (ti[0] == bi);
#pragma unroll
        for (int j = 0; j < TOPK - 1; ++j) {
            tv[j] = win ? tv[j + 1] : tv[j];
            ti[j] = win ? ti[j + 1] : ti[j];
        }
        if (win) { tv[TOPK - 1] = 0.0f; ti[TOPK - 1] = SENT_I; }
        if (lane == k) { outv = bv; outi = bi; }
    }
    if (lane < TOPK) {
        const int g = g0 + wj;
        ppack[(g * CHUNKS + c) * TOPK + lane] =
            make_int2(__float_as_int(outv), outi);
    }
}

// K2: one block (one wave) per GT. Lane t (<CHUNKS) holds chunk t's sorted
// 10-list (packed int2); lanes >= CHUNKS hold sentinels and lose every round.
// Phase 1: 10 rounds of wave selection -> exact top-10 (lanes 0..9 hold them).
// Phase 2: broadcast all 10 winners, issue ALL their loads up front (ILP),
// then for each positive winner all 64 lanes compute that anchor's metric
// against THEIR OWN GT and butterfly-argmax (m, g) -> out_idx.
// Duplicate winners across GT columns write identical values — benign.
__global__ __launch_bounds__(64) void merge_assign_kernel(
    const int2*  __restrict__ ppack,
    const float* __restrict__ pd_scores,
    const float* __restrict__ pd_bboxes,
    const float* __restrict__ anc_points,
    const float* __restrict__ gt_bboxes,
    int* __restrict__ out_fg,
    int* __restrict__ out_idx)
{
    const int g    = blockIdx.x;
    const int lane = threadIdx.x;   // == chunk for loading; == GT for argmax

    float4 mygt = ((const float4*)gt_bboxes)[lane];
    float  myga = (mygt.z - mygt.x) * (mygt.w - mygt.y);

    float tv[TOPK]; int ti[TOPK];
    if (lane < CHUNKS) {
        const int2* pp = ppack + (g * CHUNKS + lane) * TOPK;
#pragma unroll
        for (int k = 0; k < TOPK; ++k) {
            int2 v = pp[k];
            tv[k] = __int_as_float(v.x); ti[k] = v.y;
        }
    } else {
#pragma unroll
        for (int k = 0; k < TOPK; ++k) { tv[k] = 0.0f; ti[k] = SENT_I; }
    }

    // ---- Phase 1: pure-shuffle selection of the global top-10 ----
    float outv = 0.0f; int outi = SENT_I;
#pragma unroll
    for (int k = 0; k < TOPK; ++k) {
        float bv = tv[0]; int bi = ti[0];
        wave_max_pair(bv, bi);
        bool win = (ti[0] == bi);
#pragma unroll
        for (int j = 0; j < TOPK - 1; ++j) {
            tv[j] = win ? tv[j + 1] : tv[j];
            ti[j] = win ? ti[j + 1] : ti[j];
        }
        if (win) { tv[TOPK - 1] = 0.0f; ti[TOPK - 1] = SENT_I; }
        if (lane == k) { outv = bv; outi = bi; }
    }

    // ---- Phase 2: broadcast winners, issue all loads, then assign ----
    float wv[TOPK]; int wa[TOPK];
#pragma unroll
    for (int k = 0; k < TOPK; ++k) {
        wv[k] = __shfl(outv, k, 64);
        wa[k] = __shfl(outi, k, 64);
    }

    float4 pb[TOPK]; float sc[TOPK]; float2 ap[TOPK];
#pragma unroll
    for (int k = 0; k < TOPK; ++k) {
        const int a = (wv[k] > 0.0f) ? wa[k] : 0;   // safe index when sentinel
        pb[k] = ((const float4*)pd_bboxes)[a];
        sc[k] = pd_scores[a];
        ap[k] = ((const float2*)anc_points)[a];
    }

#pragma unroll
    for (int k = 0; k < TOPK; ++k) {
        if (wv[k] > 0.0f) {         // wave-uniform: winner k is foreground
            const int a = wa[k];
            float parea = (pb[k].z - pb[k].x) * (pb[k].w - pb[k].y);
            bool in = (ap[k].x >= mygt.x) && (ap[k].x <= mygt.z) &&
                      (ap[k].y >= mygt.y) && (ap[k].y <= mygt.w);
            float m = iou_metric(pb[k].x, pb[k].y, pb[k].z, pb[k].w, parea,
                                 in ? sc[k] : 0.0f,   // exact-0 when outside
                                 mygt.x, mygt.y, mygt.z, mygt.w, myga);
            // butterfly argmax over (m, gt=lane); lowest g on ties = first-max
            float av = m; int ag = lane;
#pragma unroll
            for (int s = 1; s < 64; s <<= 1) {
                float ov = __shfl_xor(av, s, 64);
                int   og = __shfl_xor(ag, s, 64);
                if ((ov > av) || ((ov == av) && (og < ag))) { av = ov; ag = og; }
            }
            if (lane == 0) { out_fg[a] = 1; out_idx[a] = ag; }
        }
    }
}

extern "C" void kernel_launch(void* const* d_in, const int* in_sizes, int n_in,
                              void* d_out, int out_size, void* d_ws, size_t ws_size,
                              hipStream_t stream) {
    const float* pd_scores  = (const float*)d_in[0];   // (A,1) f32
    const float* pd_bboxes  = (const float*)d_in[1];   // (A,4) f32
    const float* anc_points = (const float*)d_in[2];   // (A,2) f32
    // d_in[3] = gt_labels (G,) int32 — unused (NUM_CLASSES==1 -> all 0)
    const float* gt_bboxes  = (const float*)d_in[4];   // (G,4) f32

    int2* ppack = (int2*)d_ws;             // 64*32*10 int2 = 160 KB

    int* out_fg  = (int*)d_out;            // [fg(A) | idx(A)] as int32
    int* out_idx = out_fg + NUM_A;

    // output zeroing is folded into topk_partial_kernel; K2 runs after it.
    dim3 g1(CHUNKS, NGROUPS);
    topk_partial_kernel<<<g1, 512, 0, stream>>>(
        pd_scores, pd_bboxes, anc_points, gt_bboxes, ppack, out_fg);
    merge_assign_kernel<<<NUM_G, 64, 0, stream>>>(
        ppack, pd_scores, pd_bboxes, anc_points, gt_bboxes,
        out_fg, out_idx);
}

// Round 5
// 101.794 us; speedup vs baseline: 1.0878x; 1.0878x over previous
//
#include <hip/hip_runtime.h>

#define NUM_A    400000
#define NUM_G    64
#define TOPK     10
#define CHUNKS   64
#define CHUNK_SZ (NUM_A / CHUNKS)   // 6250
#define GGROUP   8                  // GTs per K1 block (= waves per block)
#define NGROUPS  (NUM_G / GGROUP)   // 8
#define NBLOCKS  (CHUNKS * NGROUPS) // 512
#define CAP      768                // per-GT candidate cap per chunk
#define SENT_I   0x7fffffff

// top_k ordering: larger value first; ties -> lower anchor index first.
// Sentinel (0.0f, SENT_I) sorts after every real candidate.
__device__ __forceinline__ bool better(float m1, int a1, float m2, int a2) {
    return (m1 > m2) || ((m1 == m2) && (a1 < a2));
}

// IoU-metric; arithmetic order identical to verified rounds (absmax=0 vs numpy).
__device__ __forceinline__ float iou_metric(
    float px1, float py1, float px2, float py2, float parea, float score,
    float gx1, float gy1, float gx2, float gy2, float garea)
{
    float ltx = fmaxf(px1, gx1);
    float lty = fmaxf(py1, gy1);
    float rbx = fminf(px2, gx2);
    float rby = fminf(py2, gy2);
    float w = fmaxf(rbx - ltx, 0.0f);
    float h = fmaxf(rby - lty, 0.0f);
    float inter = w * h;
    float iou = inter / (parea + garea - inter);   // denom >= 64 always
    float iou2 = iou * iou;
    float iou6 = iou2 * iou2 * iou2;
    return score * iou6;
}

// Wave-wide (64-lane) butterfly max of (value, anchor) under better().
__device__ __forceinline__ void wave_max_pair(float& bv, int& bi) {
#pragma unroll
    for (int s = 1; s < 64; s <<= 1) {
        float ov = __shfl_xor(bv, s, 64);
        int   oi = __shfl_xor(bi, s, 64);
        if (better(ov, oi, bv, bi)) { bv = ov; bi = oi; }
    }
}

// K1: block = (chunk c, gt-group gg), 8 waves (512 threads), 512 blocks.
// (R4 post-mortem: CHUNKS=32/256 blocks = 1 block/CU regressed ~3.5 us —
// keep 2 blocks/CU; block-parallelism beats fixed-cost amortization here.)
// Also zeroes the output buffers (folded memset, verified in R1).
// Phase A: in-box test; ballot-compacted append to per-GT LDS candidate lists.
// Phase B: wave j evaluates GT j's candidates into per-lane sorted top-10,
// then 10 rounds of register-only wave-butterfly selection; partials are
// packed (float-bits, idx) int2 — one dwordx2 store/load per pair.
// NOTE (R2 post-mortem): do NOT fuse the merge in here via device-scope
// semaphores — per-block __threadfence() (L2 wb/inv) cost ~75 us. The kernel
// boundary's runtime-managed flush is far cheaper.
__global__ __launch_bounds__(512) void topk_partial_kernel(
    const float* __restrict__ pd_scores,
    const float* __restrict__ pd_bboxes,
    const float* __restrict__ anc_points,
    const float* __restrict__ gt_bboxes,
    int2*  __restrict__ ppack,
    int*   __restrict__ out_zero)      // [fg(A) | idx(A)] to be zeroed
{
    const int c   = blockIdx.x;
    const int gg  = blockIdx.y;
    const int tid = threadIdx.x;
    const int g0  = gg * GGROUP;

    // ---- folded output memset: 200000 int4 over 262144 threads ----
    {
        const int t = (gg * CHUNKS + c) * 512 + tid;
        if (t < (2 * NUM_A) / 4) ((int4*)out_zero)[t] = make_int4(0, 0, 0, 0);
    }

    __shared__ int s_cnt[GGROUP];
    __shared__ int s_cand[GGROUP][CAP];

    if (tid < GGROUP) s_cnt[tid] = 0;

    float gx1[GGROUP], gy1[GGROUP], gx2[GGROUP], gy2[GGROUP];
#pragma unroll
    for (int j = 0; j < GGROUP; ++j) {
        float4 gb = ((const float4*)gt_bboxes)[g0 + j];
        gx1[j] = gb.x; gy1[j] = gb.y; gx2[j] = gb.z; gy2[j] = gb.w;
    }
    __syncthreads();

    const int lane = tid & 63;
    const unsigned long long lmlt = (1ull << lane) - 1ull;   // lanemask_lt

    // ---- Phase A: candidate collection (ballot-compacted) ----
    const int p0 = c * (CHUNK_SZ / 2);          // float4 = 2 anchors
    const int p1 = p0 + CHUNK_SZ / 2;
    for (int p = p0 + tid; p < p1; p += 512) {
        float4 aq = ((const float4*)anc_points)[p];
        const int a2 = 2 * p;
#pragma unroll
        for (int j = 0; j < GGROUP; ++j) {
            bool in0 = (aq.x >= gx1[j]) && (aq.x <= gx2[j]) &&
                       (aq.y >= gy1[j]) && (aq.y <= gy2[j]);
            bool in1 = (aq.z >= gx1[j]) && (aq.z <= gx2[j]) &&
                       (aq.w >= gy1[j]) && (aq.w <= gy2[j]);
            unsigned long long b0 = __ballot(in0);
            unsigned long long b1 = __ballot(in1);
            if (b0 | b1) {                       // wave-uniform
                int c0  = __popcll(b0);
                int tot = c0 + __popcll(b1);
                int base;
                if (lane == 0) base = atomicAdd(&s_cnt[j], tot);
                base = __shfl(base, 0, 64);
                if (in0) {
                    int q = base + __popcll(b0 & lmlt);
                    if (q < CAP) s_cand[j][q] = a2;
                }
                if (in1) {
                    int q = base + c0 + __popcll(b1 & lmlt);
                    if (q < CAP) s_cand[j][q] = a2 + 1;
                }
            }
        }
    }
    __syncthreads();

    // ---- Phase B: per-wave candidate evaluation ----
    const int wj = tid >> 6;       // wave = GT within group

    float4 gb = ((const float4*)gt_bboxes)[g0 + wj];   // wave-uniform
    const float garea = (gb.z - gb.x) * (gb.w - gb.y);
    const int n = min(s_cnt[wj], CAP);

    float tv[TOPK]; int ti[TOPK];
#pragma unroll
    for (int k = 0; k < TOPK; ++k) { tv[k] = 0.0f; ti[k] = SENT_I; }

    for (int i = lane; i < n; i += 64) {
        const int a = s_cand[wj][i];
        float4 pb = ((const float4*)pd_bboxes)[a];
        float sc = pd_scores[a];
        float parea = (pb.z - pb.x) * (pb.w - pb.y);
        float m = iou_metric(pb.x, pb.y, pb.z, pb.w, parea, sc,
                             gb.x, gb.y, gb.z, gb.w, garea);
        // list order is arbitrary -> need full (v,idx) compare
        if (better(m, a, tv[TOPK - 1], ti[TOPK - 1])) {
#pragma unroll
            for (int k = TOPK - 1; k >= 1; --k) {
                bool gp = better(m, a, tv[k - 1], ti[k - 1]);
                bool gc = better(m, a, tv[k],     ti[k]);
                tv[k] = gp ? tv[k - 1] : (gc ? m : tv[k]);
                ti[k] = gp ? ti[k - 1] : (gc ? a : ti[k]);
            }
            if (better(m, a, tv[0], ti[0])) { tv[0] = m; ti[0] = a; }
        }
    }

    // ---- 10-round wave selection: 64 sorted lists -> chunk top-10 ----
    float outv = 0.0f; int outi = SENT_I;
#pragma unroll
    for (int k = 0; k < TOPK; ++k) {
        float bv = tv[0]; int bi = ti[0];
        wave_max_pair(bv, bi);
        bool win = (ti[0] == bi);
#pragma unroll
        for (int j = 0; j < TOPK - 1; ++j) {
            tv[j] = win ? tv[j + 1] : tv[j];
            ti[j] = win ? ti[j + 1] : ti[j];
        }
        if (win) { tv[TOPK - 1] = 0.0f; ti[TOPK - 1] = SENT_I; }
        if (lane == k) { outv = bv; outi = bi; }
    }
    if (lane < TOPK) {
        const int g = g0 + wj;
        ppack[(g * CHUNKS + c) * TOPK + lane] =
            make_int2(__float_as_int(outv), outi);
    }
}

// K2: one block (one wave) per GT. Lane t holds chunk t's sorted 10-list
// (packed int2).
// Phase 1: 10 rounds of wave selection -> exact top-10 (lanes 0..9 hold them).
// Phase 2: broadcast all 10 winners, issue ALL their loads up front (ILP),
// then for each positive winner all 64 lanes compute that anchor's metric
// against THEIR OWN GT and butterfly-argmax (m, g) -> out_idx.
// Duplicate winners across GT columns write identical values — benign.
__global__ __launch_bounds__(64) void merge_assign_kernel(
    const int2*  __restrict__ ppack,
    const float* __restrict__ pd_scores,
    const float* __restrict__ pd_bboxes,
    const float* __restrict__ anc_points,
    const float* __restrict__ gt_bboxes,
    int* __restrict__ out_fg,
    int* __restrict__ out_idx)
{
    const int g    = blockIdx.x;
    const int lane = threadIdx.x;   // == chunk for loading; == GT for argmax

    float4 mygt = ((const float4*)gt_bboxes)[lane];
    float  myga = (mygt.z - mygt.x) * (mygt.w - mygt.y);

    float tv[TOPK]; int ti[TOPK];
    {
        const int2* pp = ppack + (g * CHUNKS + lane) * TOPK;
#pragma unroll
        for (int k = 0; k < TOPK; ++k) {
            int2 v = pp[k];
            tv[k] = __int_as_float(v.x); ti[k] = v.y;
        }
    }

    // ---- Phase 1: pure-shuffle selection of the global top-10 ----
    float outv = 0.0f; int outi = SENT_I;
#pragma unroll
    for (int k = 0; k < TOPK; ++k) {
        float bv = tv[0]; int bi = ti[0];
        wave_max_pair(bv, bi);
        bool win = (ti[0] == bi);
#pragma unroll
        for (int j = 0; j < TOPK - 1; ++j) {
            tv[j] = win ? tv[j + 1] : tv[j];
            ti[j] = win ? ti[j + 1] : ti[j];
        }
        if (win) { tv[TOPK - 1] = 0.0f; ti[TOPK - 1] = SENT_I; }
        if (lane == k) { outv = bv; outi = bi; }
    }

    // ---- Phase 2: broadcast winners, issue all loads, then assign ----
    float wv[TOPK]; int wa[TOPK];
#pragma unroll
    for (int k = 0; k < TOPK; ++k) {
        wv[k] = __shfl(outv, k, 64);
        wa[k] = __shfl(outi, k, 64);
    }

    float4 pb[TOPK]; float sc[TOPK]; float2 ap[TOPK];
#pragma unroll
    for (int k = 0; k < TOPK; ++k) {
        const int a = (wv[k] > 0.0f) ? wa[k] : 0;   // safe index when sentinel
        pb[k] = ((const float4*)pd_bboxes)[a];
        sc[k] = pd_scores[a];
        ap[k] = ((const float2*)anc_points)[a];
    }

#pragma unroll
    for (int k = 0; k < TOPK; ++k) {
        if (wv[k] > 0.0f) {         // wave-uniform: winner k is foreground
            const int a = wa[k];
            float parea = (pb[k].z - pb[k].x) * (pb[k].w - pb[k].y);
            bool in = (ap[k].x >= mygt.x) && (ap[k].x <= mygt.z) &&
                      (ap[k].y >= mygt.y) && (ap[k].y <= mygt.w);
            float m = iou_metric(pb[k].x, pb[k].y, pb[k].z, pb[k].w, parea,
                                 in ? sc[k] : 0.0f,   // exact-0 when outside
                                 mygt.x, mygt.y, mygt.z, mygt.w, myga);
            // butterfly argmax over (m, gt=lane); lowest g on ties = first-max
            float av = m; int ag = lane;
#pragma unroll
            for (int s = 1; s < 64; s <<= 1) {
                float ov = __shfl_xor(av, s, 64);
                int   og = __shfl_xor(ag, s, 64);
                if ((ov > av) || ((ov == av) && (og < ag))) { av = ov; ag = og; }
            }
            if (lane == 0) { out_fg[a] = 1; out_idx[a] = ag; }
        }
    }
}

extern "C" void kernel_launch(void* const* d_in, const int* in_sizes, int n_in,
                              void* d_out, int out_size, void* d_ws, size_t ws_size,
                              hipStream_t stream) {
    const float* pd_scores  = (const float*)d_in[0];   // (A,1) f32
    const float* pd_bboxes  = (const float*)d_in[1];   // (A,4) f32
    const float* anc_points = (const float*)d_in[2];   // (A,2) f32
    // d_in[3] = gt_labels (G,) int32 — unused (NUM_CLASSES==1 -> all 0)
    const float* gt_bboxes  = (const float*)d_in[4];   // (G,4) f32

    int2* ppack = (int2*)d_ws;             // 64*64*10 int2 = 320 KB

    int* out_fg  = (int*)d_out;            // [fg(A) | idx(A)] as int32
    int* out_idx = out_fg + NUM_A;

    // output zeroing is folded into topk_partial_kernel; K2 runs after it.
    dim3 g1(CHUNKS, NGROUPS);
    topk_partial_kernel<<<g1, 512, 0, stream>>>(
        pd_scores, pd_bboxes, anc_points, gt_bboxes, ppack, out_fg);
    merge_assign_kernel<<<NUM_G, 64, 0, stream>>>(
        ppack, pd_scores, pd_bboxes, anc_points, gt_bboxes,
        out_fg, out_idx);
}